// Round 4
// baseline (1046.023 us; speedup 1.0000x reference)
//
#include <hip/hip_runtime.h>
#include <stdint.h>

#define HIDDEN 2048
#define NHEADS 16
#define HDIM 128
#define BATCH 2
#define SEQ 2048
#define MTOT (BATCH*SEQ)   // 4096

typedef __attribute__((ext_vector_type(4))) float f32x4;
typedef __attribute__((ext_vector_type(8))) short s16x8;
typedef __attribute__((ext_vector_type(4))) short s16x4;

// round-to-nearest-even f32 -> bf16 bits
static __device__ __forceinline__ unsigned short f2bf(float f) {
  unsigned u = __float_as_uint(f);
  u += 0x7fff + ((u >> 16) & 1);
  return (unsigned short)(u >> 16);
}

static __device__ __forceinline__ f32x4 mfma32(s16x8 a, s16x8 b, f32x4 c) {
  return __builtin_amdgcn_mfma_f32_16x16x32_bf16(a, b, c, 0, 0, 0);
}
static __device__ __forceinline__ f32x4 mfma16(s16x4 a, s16x4 b, f32x4 c) {
  return __builtin_amdgcn_mfma_f32_16x16x16bf16_1k(a, b, c, 0, 0, 0);
}

__global__ void cast_f32_to_bf16(const float* __restrict__ in,
                                 unsigned short* __restrict__ out, int n4) {
  int i = blockIdx.x * blockDim.x + threadIdx.x;
  if (i >= n4) return;
  float4 v = reinterpret_cast<const float4*>(in)[i];
  ushort4 o;
  o.x = f2bf(v.x); o.y = f2bf(v.y); o.z = f2bf(v.z); o.w = f2bf(v.w);
  reinterpret_cast<ushort4*>(out)[i] = o;
}

// C[m,n] = sum_k A[m,k]*B[n,k] + bias[n]
// A [M,K] bf16 row-major; B [N,K] row-major (bf16 if B_BF16 else fp32 cast inline).
// OUT_TRANS: write C^T split per batch: Cout[(row>>11)*N + col][row&2047] (V-proj -> VT[b][d][s]).
// 256 thr = 4 waves; block tile 128x128; wave tile 64x64 (acc 4x4 of 16x16 frags).
template<bool OUT_BF16, bool B_BF16, bool OUT_TRANS>
__global__ __launch_bounds__(256) void gemm_abt(
    const unsigned short* __restrict__ A, const void* __restrict__ Bw,
    const float* __restrict__ bias, void* __restrict__ Cout,
    int M, int N, int K)
{
  const int lane = threadIdx.x & 63;
  const int wid  = threadIdx.x >> 6;
  const int g = lane >> 4, lr = lane & 15;
  const int m0 = blockIdx.x * 128 + (wid >> 1) * 64;
  const int n0 = blockIdx.y * 128 + (wid & 1) * 64;
  f32x4 acc[4][4] = {};
  const unsigned short* Ap = A + (size_t)(m0 + lr) * K + g * 8;
  const unsigned short* Bh = B_BF16 ? (const unsigned short*)Bw + (size_t)(n0 + lr) * K + g * 8 : nullptr;
  const float*          Bf = B_BF16 ? nullptr : (const float*)Bw + (size_t)(n0 + lr) * K + g * 8;
  for (int k0 = 0; k0 < K; k0 += 32) {
    s16x8 a[4], b[4];
#pragma unroll
    for (int i = 0; i < 4; ++i)
      a[i] = *reinterpret_cast<const s16x8*>(Ap + (size_t)i * 16 * K + k0);
#pragma unroll
    for (int i = 0; i < 4; ++i) {
      if (B_BF16) {
        b[i] = *reinterpret_cast<const s16x8*>(Bh + (size_t)i * 16 * K + k0);
      } else {
        const float* bp = Bf + (size_t)i * 16 * K + k0;
        float4 lo = *reinterpret_cast<const float4*>(bp);
        float4 hi = *reinterpret_cast<const float4*>(bp + 4);
        s16x8 t;
        t[0] = (short)f2bf(lo.x); t[1] = (short)f2bf(lo.y);
        t[2] = (short)f2bf(lo.z); t[3] = (short)f2bf(lo.w);
        t[4] = (short)f2bf(hi.x); t[5] = (short)f2bf(hi.y);
        t[6] = (short)f2bf(hi.z); t[7] = (short)f2bf(hi.w);
        b[i] = t;
      }
    }
#pragma unroll
    for (int i = 0; i < 4; ++i)
#pragma unroll
      for (int j = 0; j < 4; ++j)
        acc[i][j] = mfma32(a[i], b[j], acc[i][j]);
  }
#pragma unroll
  for (int i = 0; i < 4; ++i)
#pragma unroll
    for (int j = 0; j < 4; ++j) {
      const int col  = n0 + j * 16 + lr;
      const float bv = bias[col];
      const int row0 = m0 + i * 16 + g * 4;
      if (OUT_TRANS) {
        s16x4 ov;
#pragma unroll
        for (int r = 0; r < 4; ++r) ov[r] = (short)f2bf(acc[i][j][r] + bv);
        const int bb = row0 >> 11, s0 = row0 & 2047;
        *reinterpret_cast<s16x4*>(
            reinterpret_cast<unsigned short*>(Cout) + ((size_t)(bb * N + col)) * SEQ + s0) = ov;
      } else {
#pragma unroll
        for (int r = 0; r < 4; ++r) {
          float v = acc[i][j][r] + bv;
          if (OUT_BF16)
            reinterpret_cast<unsigned short*>(Cout)[(size_t)(row0 + r) * N + col] = f2bf(v);
          else
            reinterpret_cast<float*>(Cout)[(size_t)(row0 + r) * N + col] = v;
        }
      }
    }
}

// Flash MQA, swapped QK^T, V pre-transposed. One wave = 16 q-rows of one (b,h).
// S^T[kv][q] frag: kv=g*4+r, q=lr -> softmax reduce = 4 regs + shfl_xor(16,32).
// PV: awT[d][q] += VT(16d x 16kv) * P^T(16kv x 16q); VT fragment = one 8B vector load.
// Defer-max (T13, THR=8): skip O-rescale unless any lane's tile-max beats m by >8.
// Output transposed: OT[b][h*128+d][q] (feeds O-proj as plain A*B^T).
__global__ __launch_bounds__(64) void mqa_attn(
    const unsigned short* __restrict__ Q,    // [B*S, 2048] bf16
    const unsigned short* __restrict__ Kx,   // [B*S, 128]  bf16
    const unsigned short* __restrict__ Vt,   // [B, 128, S] bf16 (transposed)
    unsigned short* __restrict__ OT)         // [B, 2048, S] bf16
{
  const int qt = gridDim.x - 1 - blockIdx.x;  // longest blocks dispatched first
  const int h  = blockIdx.y;
  const int b  = blockIdx.z;
  const int lane = threadIdx.x;
  const int g = lane >> 4, lr = lane & 15;
  const int q0 = qt * 16;
  const int qglob = q0 + lr;

  const unsigned short* Qb = Q  + (size_t)(b * SEQ + q0 + lr) * HIDDEN + h * HDIM;
  const unsigned short* Kb = Kx + (size_t)b * SEQ * HDIM;
  const unsigned short* Vb = Vt + (size_t)b * HDIM * SEQ;

  s16x8 qf[4];
#pragma unroll
  for (int c = 0; c < 4; ++c)
    qf[c] = *reinterpret_cast<const s16x8*>(Qb + c * 32 + g * 8);

  float m = -1e30f, lsum = 0.f;
  f32x4 acc[8] = {};
  const float scale = 0.08838834764831845f;  // 1/sqrt(128)

  for (int j = 0; j <= qt; ++j) {
    const int k0 = j * 16;
    f32x4 s = {0.f, 0.f, 0.f, 0.f};
#pragma unroll
    for (int c = 0; c < 4; ++c) {
      s16x8 kf = *reinterpret_cast<const s16x8*>(
          Kb + (size_t)(k0 + lr) * HDIM + c * 32 + g * 8);
      s = mfma32(kf, qf[c], s);   // S^T[kv][q]
    }
    float sv[4];
    if (j == qt) {
#pragma unroll
      for (int r = 0; r < 4; ++r) {
        const int kv = k0 + g * 4 + r;
        sv[r] = (kv <= qglob) ? s[r] * scale : -1e30f;
      }
    } else {
#pragma unroll
      for (int r = 0; r < 4; ++r) sv[r] = s[r] * scale;
    }
    float tmax = fmaxf(fmaxf(sv[0], sv[1]), fmaxf(sv[2], sv[3]));
    tmax = fmaxf(tmax, __shfl_xor(tmax, 16));
    tmax = fmaxf(tmax, __shfl_xor(tmax, 32));
    if (__any(tmax > m + 8.f)) {          // defer-max: rescale only when needed
      const float mnew  = fmaxf(m, tmax);
      const float alpha = __expf(m - mnew);
      lsum *= alpha;
#pragma unroll
      for (int t = 0; t < 8; ++t)
#pragma unroll
        for (int r2 = 0; r2 < 4; ++r2) acc[t][r2] *= alpha;
      m = mnew;
    }
    float p[4], tsum = 0.f;
#pragma unroll
    for (int r = 0; r < 4; ++r) { p[r] = __expf(sv[r] - m); tsum += p[r]; }
    tsum += __shfl_xor(tsum, 16);
    tsum += __shfl_xor(tsum, 32);
    lsum += tsum;
    s16x4 pb;
#pragma unroll
    for (int r = 0; r < 4; ++r) pb[r] = (short)f2bf(p[r]);
    // PV: awT[d][q] += VT(16d x 16kv) * P^T(16kv x 16q), per 16-wide d tile
#pragma unroll
    for (int t = 0; t < 8; ++t) {
      s16x4 vf = *reinterpret_cast<const s16x4*>(
          Vb + (size_t)(t * 16 + lr) * SEQ + k0 + g * 4);
      acc[t] = mfma16(vf, pb, acc[t]);
    }
  }
  const float inv = 1.0f / lsum;
#pragma unroll
  for (int t = 0; t < 8; ++t)
#pragma unroll
    for (int r = 0; r < 4; ++r) {
      const int d = h * HDIM + t * 16 + g * 4 + r;
      OT[(size_t)(b * HIDDEN + d) * SEQ + qglob] = f2bf(acc[t][r] * inv);
    }
}

extern "C" void kernel_launch(void* const* d_in, const int* in_sizes, int n_in,
                              void* d_out, int out_size, void* d_ws, size_t ws_size,
                              hipStream_t stream) {
  (void)in_sizes; (void)n_in; (void)out_size;
  const float* x    = (const float*)d_in[0];
  // d_in[1] = attention_mask (causal tril) — hardcoded in mqa_attn
  const float* qw_w = (const float*)d_in[2];
  const float* qw_b = (const float*)d_in[3];
  const float* kw_w = (const float*)d_in[4];
  const float* kw_b = (const float*)d_in[5];
  const float* vw_w = (const float*)d_in[6];
  const float* vw_b = (const float*)d_in[7];
  const float* ow_w = (const float*)d_in[8];
  const float* ow_b = (const float*)d_in[9];
  float* out = (float*)d_out;

  // d_out doubles as scratch until the O-proj overwrites it:
  //   [0, 16.78M)      xb  [4096,2048] bf16 (dead after V-proj)
  //   [16.78M, 33.55M) qxb [4096,2048] bf16 (dead after attn)
  char* ob = (char*)d_out;
  char* ws = (char*)d_ws;
  unsigned short* xb  = (unsigned short*)(ob);
  unsigned short* qxb = (unsigned short*)(ob + 16777216);

  cast_f32_to_bf16<<<8192, 256, 0, stream>>>(x, xb, 2097152);

  if (ws_size >= 27262976) {
    // FAST path: weights pre-cast to bf16.
    //   ws[0, 8.39M)       qwb (dead after Q-proj)  } overwritten by awT
    //   ws[8.39M, 8.91M)   kwb (dead after K-proj)  } after projections
    //   ws[8.91M, 9.44M)   vwb (dead after V-proj)  }
    //   ws[0, 16.78M)      awT (written by attn, read by O-proj)
    //   ws[16.78M, 25.17M) owb (live till end)
    //   ws[25.17M, 26.21M) kxb
    //   ws[26.21M, 27.26M) vtb (V transposed [B,128,S])
    unsigned short* qwb = (unsigned short*)(ws);
    unsigned short* kwb = (unsigned short*)(ws + 8388608);
    unsigned short* vwb = (unsigned short*)(ws + 8912896);
    unsigned short* awT = (unsigned short*)(ws);
    unsigned short* owb = (unsigned short*)(ws + 16777216);
    unsigned short* kxb = (unsigned short*)(ws + 25165824);
    unsigned short* vtb = (unsigned short*)(ws + 26214400);

    cast_f32_to_bf16<<<4096, 256, 0, stream>>>(qw_w, qwb, 1048576);
    cast_f32_to_bf16<<< 256, 256, 0, stream>>>(kw_w, kwb,   65536);
    cast_f32_to_bf16<<< 256, 256, 0, stream>>>(vw_w, vwb,   65536);
    cast_f32_to_bf16<<<4096, 256, 0, stream>>>(ow_w, owb, 1048576);

    gemm_abt<true , true, false><<<dim3(32, 16), 256, 0, stream>>>(xb, qwb, qw_b, qxb, MTOT, HIDDEN, HIDDEN);
    gemm_abt<true , true, false><<<dim3(32,  1), 256, 0, stream>>>(xb, kwb, kw_b, kxb, MTOT, HDIM,  HIDDEN);
    gemm_abt<true , true, true ><<<dim3(32,  1), 256, 0, stream>>>(xb, vwb, vw_b, vtb, MTOT, HDIM,  HIDDEN);

    mqa_attn<<<dim3(SEQ / 16, NHEADS, BATCH), 64, 0, stream>>>(qxb, kxb, vtb, awT);

    gemm_abt<false, true, false><<<dim3(32, 16), 256, 0, stream>>>(awT, owb, ow_b, out, MTOT, HIDDEN, HIDDEN);
  } else {
    // FALLBACK (proven 18.87 MB layout): fp32 weights cast inline in the GEMM.
    //   ws[0, 16.78M)      awT;  ws[16.78M, 17.83M) kxb;  ws[17.83M, 18.87M) vtb
    if (ws_size < 18874368) return;
    unsigned short* awT = (unsigned short*)(ws);
    unsigned short* kxb = (unsigned short*)(ws + 16777216);
    unsigned short* vtb = (unsigned short*)(ws + 17825792);

    gemm_abt<true , false, false><<<dim3(32, 16), 256, 0, stream>>>(xb, qw_w, qw_b, qxb, MTOT, HIDDEN, HIDDEN);
    gemm_abt<true , false, false><<<dim3(32,  1), 256, 0, stream>>>(xb, kw_w, kw_b, kxb, MTOT, HDIM,  HIDDEN);
    gemm_abt<true , false, true ><<<dim3(32,  1), 256, 0, stream>>>(xb, vw_w, vw_b, vtb, MTOT, HDIM,  HIDDEN);

    mqa_attn<<<dim3(SEQ / 16, NHEADS, BATCH), 64, 0, stream>>>(qxb, kxb, vtb, awT);

    gemm_abt<false, false, false><<<dim3(32, 16), 256, 0, stream>>>(awT, ow_w, ow_b, out, MTOT, HIDDEN, HIDDEN);
  }
}

// Round 5
// 551.309 us; speedup vs baseline: 1.8973x; 1.8973x over previous
//
#include <hip/hip_runtime.h>
#include <stdint.h>

#define HIDDEN 2048
#define NHEADS 16
#define HDIM 128
#define BATCH 2
#define SEQ 2048
#define MTOT (BATCH*SEQ)   // 4096

typedef __attribute__((ext_vector_type(4))) float f32x4;
typedef __attribute__((ext_vector_type(8))) short s16x8;
typedef __attribute__((ext_vector_type(4))) short s16x4;

// round-to-nearest-even f32 -> bf16 bits
static __device__ __forceinline__ unsigned short f2bf(float f) {
  unsigned u = __float_as_uint(f);
  u += 0x7fff + ((u >> 16) & 1);
  return (unsigned short)(u >> 16);
}

static __device__ __forceinline__ f32x4 mfma32(s16x8 a, s16x8 b, f32x4 c) {
  return __builtin_amdgcn_mfma_f32_16x16x32_bf16(a, b, c, 0, 0, 0);
}
static __device__ __forceinline__ f32x4 mfma16(s16x4 a, s16x4 b, f32x4 c) {
  return __builtin_amdgcn_mfma_f32_16x16x16bf16_1k(a, b, c, 0, 0, 0);
}

__global__ void cast_f32_to_bf16(const float* __restrict__ in,
                                 unsigned short* __restrict__ out, int n4) {
  int i = blockIdx.x * blockDim.x + threadIdx.x;
  if (i >= n4) return;
  float4 v = reinterpret_cast<const float4*>(in)[i];
  ushort4 o;
  o.x = f2bf(v.x); o.y = f2bf(v.y); o.z = f2bf(v.z); o.w = f2bf(v.w);
  reinterpret_cast<ushort4*>(out)[i] = o;
}

// C[m,n] = sum_k A[m,k]*B[n,k] + bias[n]
// A [M,K] bf16 row-major; B [N,K] row-major (bf16 if B_BF16 else fp32 cast inline).
// 256 thr = 4 waves; block tile 128x128; wave tile 64x64 (acc 4x4 of 16x16 frags).
template<bool OUT_BF16, bool B_BF16>
__global__ __launch_bounds__(256) void gemm_abt(
    const unsigned short* __restrict__ A, const void* __restrict__ Bw,
    const float* __restrict__ bias, void* __restrict__ Cout,
    int M, int N, int K)
{
  const int lane = threadIdx.x & 63;
  const int wid  = threadIdx.x >> 6;
  const int g = lane >> 4, lr = lane & 15;
  const int m0 = blockIdx.x * 128 + (wid >> 1) * 64;
  const int n0 = blockIdx.y * 128 + (wid & 1) * 64;
  f32x4 acc[4][4] = {};
  const unsigned short* Ap = A + (size_t)(m0 + lr) * K + g * 8;
  const unsigned short* Bh = B_BF16 ? (const unsigned short*)Bw + (size_t)(n0 + lr) * K + g * 8 : nullptr;
  const float*          Bf = B_BF16 ? nullptr : (const float*)Bw + (size_t)(n0 + lr) * K + g * 8;
  for (int k0 = 0; k0 < K; k0 += 32) {
    s16x8 a[4], b[4];
#pragma unroll
    for (int i = 0; i < 4; ++i)
      a[i] = *reinterpret_cast<const s16x8*>(Ap + (size_t)i * 16 * K + k0);
#pragma unroll
    for (int i = 0; i < 4; ++i) {
      if (B_BF16) {
        b[i] = *reinterpret_cast<const s16x8*>(Bh + (size_t)i * 16 * K + k0);
      } else {
        const float* bp = Bf + (size_t)i * 16 * K + k0;
        float4 lo = *reinterpret_cast<const float4*>(bp);
        float4 hi = *reinterpret_cast<const float4*>(bp + 4);
        s16x8 t;
        t[0] = (short)f2bf(lo.x); t[1] = (short)f2bf(lo.y);
        t[2] = (short)f2bf(lo.z); t[3] = (short)f2bf(lo.w);
        t[4] = (short)f2bf(hi.x); t[5] = (short)f2bf(hi.y);
        t[6] = (short)f2bf(hi.z); t[7] = (short)f2bf(hi.w);
        b[i] = t;
      }
    }
#pragma unroll
    for (int i = 0; i < 4; ++i)
#pragma unroll
      for (int j = 0; j < 4; ++j)
        acc[i][j] = mfma32(a[i], b[j], acc[i][j]);
  }
#pragma unroll
  for (int i = 0; i < 4; ++i)
#pragma unroll
    for (int j = 0; j < 4; ++j) {
      const int col  = n0 + j * 16 + lr;
      const float bv = bias[col];
      const int row0 = m0 + i * 16 + g * 4;
#pragma unroll
      for (int r = 0; r < 4; ++r) {
        float v = acc[i][j][r] + bv;
        if (OUT_BF16)
          reinterpret_cast<unsigned short*>(Cout)[(size_t)(row0 + r) * N + col] = f2bf(v);
        else
          reinterpret_cast<float*>(Cout)[(size_t)(row0 + r) * N + col] = v;
      }
    }
}

// Flash MQA, swapped QK^T, QBLK=32 (two 16-q subtiles per wave).
// Per kv-step the 4 K vector loads and 32 V scalar loads are SHARED across both
// subtiles (K frags are lane-row-indexed -> identical registers). V stays
// row-major [s][d] (round-4's VT stride-4096 gather was a 2.3x regression).
// S^T[kv][q] frag: kv=g*4+r, q=lr -> softmax reduce = 4 regs + shfl_xor(16,32).
// Defer-max (T13, THR=8): skip O-rescale unless a lane's tile-max beats m by >8.
// Output transposed: OT[b][h*128+d][q] (feeds O-proj as plain A*B^T).
__global__ __launch_bounds__(64) void mqa_attn(
    const unsigned short* __restrict__ Q,    // [B*S, 2048] bf16
    const unsigned short* __restrict__ Kx,   // [B*S, 128]  bf16
    const unsigned short* __restrict__ Vx,   // [B*S, 128]  bf16
    unsigned short* __restrict__ OT)         // [B, 2048, S] bf16
{
  const int qt = gridDim.x - 1 - blockIdx.x;  // longest blocks first
  const int h  = blockIdx.y;
  const int b  = blockIdx.z;
  const int lane = threadIdx.x;
  const int g = lane >> 4, lr = lane & 15;
  const int q0 = qt * 32;

  const unsigned short* Kb = Kx + (size_t)b * SEQ * HDIM;
  const unsigned short* Vb = Vx + (size_t)b * SEQ * HDIM;

  s16x8 qf[2][4];
  int qglob[2], dt[2];
#pragma unroll
  for (int s = 0; s < 2; ++s) {
    qglob[s] = q0 + s * 16 + lr;
    dt[s]    = qt * 2 + s;
    const unsigned short* Qb =
        Q + (size_t)(b * SEQ + q0 + s * 16 + lr) * HIDDEN + h * HDIM;
#pragma unroll
    for (int c = 0; c < 4; ++c)
      qf[s][c] = *reinterpret_cast<const s16x8*>(Qb + c * 32 + g * 8);
  }

  float m[2] = {-1e30f, -1e30f}, lsum[2] = {0.f, 0.f};
  f32x4 acc[2][8] = {};
  const float scale = 0.08838834764831845f;  // 1/sqrt(128)

  const int jmax = qt * 2 + 1;
  for (int j = 0; j <= jmax; ++j) {
    const int k0 = j * 16;
    s16x8 kf[4];
#pragma unroll
    for (int c = 0; c < 4; ++c)
      kf[c] = *reinterpret_cast<const s16x8*>(
          Kb + (size_t)(k0 + lr) * HDIM + c * 32 + g * 8);
    s16x4 pb[2];
#pragma unroll
    for (int s = 0; s < 2; ++s) {
      f32x4 sc = {0.f, 0.f, 0.f, 0.f};
#pragma unroll
      for (int c = 0; c < 4; ++c) sc = mfma32(kf[c], qf[s][c], sc);
      float sv[4];
      if (j >= dt[s]) {            // diagonal or beyond: apply causal mask
#pragma unroll
        for (int r = 0; r < 4; ++r) {
          const int kv = k0 + g * 4 + r;
          sv[r] = (kv <= qglob[s]) ? sc[r] * scale : -1e30f;
        }
      } else {                     // full tile, no mask
#pragma unroll
        for (int r = 0; r < 4; ++r) sv[r] = sc[r] * scale;
      }
      float tmax = fmaxf(fmaxf(sv[0], sv[1]), fmaxf(sv[2], sv[3]));
      tmax = fmaxf(tmax, __shfl_xor(tmax, 16));
      tmax = fmaxf(tmax, __shfl_xor(tmax, 32));
      if (__any(tmax > m[s] + 8.f)) {   // defer-max rescale
        const float mnew  = fmaxf(m[s], tmax);
        const float alpha = __expf(m[s] - mnew);
        lsum[s] *= alpha;
#pragma unroll
        for (int t = 0; t < 8; ++t)
#pragma unroll
          for (int r = 0; r < 4; ++r) acc[s][t][r] *= alpha;
        m[s] = mnew;
      }
      float p[4], ts = 0.f;
#pragma unroll
      for (int r = 0; r < 4; ++r) { p[r] = __expf(sv[r] - m[s]); ts += p[r]; }
      ts += __shfl_xor(ts, 16);
      ts += __shfl_xor(ts, 32);
      lsum[s] += ts;
#pragma unroll
      for (int r = 0; r < 4; ++r) pb[s][r] = (short)f2bf(p[r]);
    }
    // PV: awT[d][q] += V^T(16d x 16kv) * P^T(16kv x 16q); V frags shared by both subtiles
#pragma unroll
    for (int t = 0; t < 8; ++t) {
      s16x4 vf;
#pragma unroll
      for (int e = 0; e < 4; ++e)
        vf[e] = (short)Vb[(size_t)(k0 + g * 4 + e) * HDIM + t * 16 + lr];
      acc[0][t] = mfma16(vf, pb[0], acc[0][t]);
      acc[1][t] = mfma16(vf, pb[1], acc[1][t]);
    }
  }
#pragma unroll
  for (int s = 0; s < 2; ++s) {
    const float inv = 1.0f / lsum[s];
#pragma unroll
    for (int t = 0; t < 8; ++t)
#pragma unroll
      for (int r = 0; r < 4; ++r) {
        const int d = h * HDIM + t * 16 + g * 4 + r;
        OT[(size_t)(b * HIDDEN + d) * SEQ + qglob[s]] = f2bf(acc[s][t][r] * inv);
      }
  }
}

extern "C" void kernel_launch(void* const* d_in, const int* in_sizes, int n_in,
                              void* d_out, int out_size, void* d_ws, size_t ws_size,
                              hipStream_t stream) {
  (void)in_sizes; (void)n_in; (void)out_size;
  const float* x    = (const float*)d_in[0];
  // d_in[1] = attention_mask (causal tril) — hardcoded in mqa_attn
  const float* qw_w = (const float*)d_in[2];
  const float* qw_b = (const float*)d_in[3];
  const float* kw_w = (const float*)d_in[4];
  const float* kw_b = (const float*)d_in[5];
  const float* vw_w = (const float*)d_in[6];
  const float* vw_b = (const float*)d_in[7];
  const float* ow_w = (const float*)d_in[8];
  const float* ow_b = (const float*)d_in[9];
  float* out = (float*)d_out;

  // d_out doubles as scratch until the O-proj overwrites it:
  //   [0, 16.78M)      xb  [4096,2048] bf16 (dead after V-proj)
  //   [16.78M, 33.55M) qxb [4096,2048] bf16 (dead after attn)
  char* ob = (char*)d_out;
  char* ws = (char*)d_ws;
  unsigned short* xb  = (unsigned short*)(ob);
  unsigned short* qxb = (unsigned short*)(ob + 16777216);

  cast_f32_to_bf16<<<8192, 256, 0, stream>>>(x, xb, 2097152);

  if (ws_size >= 27262976) {
    // FAST path: weights pre-cast to bf16.
    //   ws[0, 8.39M)       qwb (dead after Q-proj)  } overwritten by awT
    //   ws[8.39M, 8.91M)   kwb (dead after K-proj)  } after projections
    //   ws[8.91M, 9.44M)   vwb (dead after V-proj)  }
    //   ws[0, 16.78M)      awT (written by attn, read by O-proj)
    //   ws[16.78M, 25.17M) owb (live till end)
    //   ws[25.17M, 26.21M) kxb
    //   ws[26.21M, 27.26M) vxb
    unsigned short* qwb = (unsigned short*)(ws);
    unsigned short* kwb = (unsigned short*)(ws + 8388608);
    unsigned short* vwb = (unsigned short*)(ws + 8912896);
    unsigned short* awT = (unsigned short*)(ws);
    unsigned short* owb = (unsigned short*)(ws + 16777216);
    unsigned short* kxb = (unsigned short*)(ws + 25165824);
    unsigned short* vxb = (unsigned short*)(ws + 26214400);

    cast_f32_to_bf16<<<4096, 256, 0, stream>>>(qw_w, qwb, 1048576);
    cast_f32_to_bf16<<< 256, 256, 0, stream>>>(kw_w, kwb,   65536);
    cast_f32_to_bf16<<< 256, 256, 0, stream>>>(vw_w, vwb,   65536);
    cast_f32_to_bf16<<<4096, 256, 0, stream>>>(ow_w, owb, 1048576);

    gemm_abt<true , true><<<dim3(32, 16), 256, 0, stream>>>(xb, qwb, qw_b, qxb, MTOT, HIDDEN, HIDDEN);
    gemm_abt<true , true><<<dim3(32,  1), 256, 0, stream>>>(xb, kwb, kw_b, kxb, MTOT, HDIM,  HIDDEN);
    gemm_abt<true , true><<<dim3(32,  1), 256, 0, stream>>>(xb, vwb, vw_b, vxb, MTOT, HDIM,  HIDDEN);

    mqa_attn<<<dim3(SEQ / 32, NHEADS, BATCH), 64, 0, stream>>>(qxb, kxb, vxb, awT);

    gemm_abt<false, true><<<dim3(32, 16), 256, 0, stream>>>(awT, owb, ow_b, out, MTOT, HIDDEN, HIDDEN);
  } else {
    // FALLBACK (proven 18.87 MB layout): fp32 weights cast inline in the GEMM.
    //   ws[0, 16.78M) awT;  ws[16.78M, 17.83M) kxb;  ws[17.83M, 18.87M) vxb
    if (ws_size < 18874368) return;
    unsigned short* awT = (unsigned short*)(ws);
    unsigned short* kxb = (unsigned short*)(ws + 16777216);
    unsigned short* vxb = (unsigned short*)(ws + 17825792);

    gemm_abt<true , false><<<dim3(32, 16), 256, 0, stream>>>(xb, qw_w, qw_b, qxb, MTOT, HIDDEN, HIDDEN);
    gemm_abt<true , false><<<dim3(32,  1), 256, 0, stream>>>(xb, kw_w, kw_b, kxb, MTOT, HDIM,  HIDDEN);
    gemm_abt<true , false><<<dim3(32,  1), 256, 0, stream>>>(xb, vw_w, vw_b, vxb, MTOT, HDIM,  HIDDEN);

    mqa_attn<<<dim3(SEQ / 32, NHEADS, BATCH), 64, 0, stream>>>(qxb, kxb, vxb, awT);

    gemm_abt<false, false><<<dim3(32, 16), 256, 0, stream>>>(awT, ow_w, ow_b, out, MTOT, HIDDEN, HIDDEN);
  }
}

// Round 6
// 319.607 us; speedup vs baseline: 3.2728x; 1.7250x over previous
//
#include <hip/hip_runtime.h>
#include <stdint.h>

#define HIDDEN 2048
#define NHEADS 16
#define HDIM 128
#define BATCH 2
#define SEQ 2048
#define MTOT (BATCH*SEQ)   // 4096
#define PW 2304            // fused qkv projection width (2048 q + 128 k + 128 v)

typedef __attribute__((ext_vector_type(4))) float f32x4;
typedef __attribute__((ext_vector_type(8))) short s16x8;
typedef __attribute__((ext_vector_type(4))) short s16x4;

// round-to-nearest-even f32 -> bf16 bits
static __device__ __forceinline__ unsigned short f2bf(float f) {
  unsigned u = __float_as_uint(f);
  u += 0x7fff + ((u >> 16) & 1);
  return (unsigned short)(u >> 16);
}

static __device__ __forceinline__ f32x4 mfma32(s16x8 a, s16x8 b, f32x4 c) {
  return __builtin_amdgcn_mfma_f32_16x16x32_bf16(a, b, c, 0, 0, 0);
}
static __device__ __forceinline__ f32x4 mfma16(s16x4 a, s16x4 b, f32x4 c) {
  return __builtin_amdgcn_mfma_f32_16x16x16bf16_1k(a, b, c, 0, 0, 0);
}

// async global->LDS, 16B per lane; lds ptr must be wave-uniform (dest = base + lane*16)
static __device__ __forceinline__ void gload16(const unsigned short* g, unsigned short* l) {
  __builtin_amdgcn_global_load_lds(
      (const __attribute__((address_space(1))) void*)g,
      (__attribute__((address_space(3))) void*)l, 16, 0, 0);
}

__global__ void cast_f32_to_bf16(const float* __restrict__ in,
                                 unsigned short* __restrict__ out, int n4) {
  int i = blockIdx.x * blockDim.x + threadIdx.x;
  if (i >= n4) return;
  float4 v = reinterpret_cast<const float4*>(in)[i];
  ushort4 o;
  o.x = f2bf(v.x); o.y = f2bf(v.y); o.z = f2bf(v.z); o.w = f2bf(v.w);
  reinterpret_cast<ushort4*>(out)[i] = o;
}

__global__ void concat_bias(const float* __restrict__ qb, const float* __restrict__ kb,
                            const float* __restrict__ vb, float* __restrict__ o) {
  int i = blockIdx.x * 256 + threadIdx.x;
  if (i < 2048) o[i] = qb[i];
  else if (i < 2176) o[i] = kb[i - 2048];
  else if (i < 2304) o[i] = vb[i - 2176];
}

// m97-structure GEMM: C[m,n] = sum_k A[m,k]*B[n,k] + bias[n], A/B bf16 row-major.
// 128x128 block tile, BK=32, 4 waves (2x2 of 64x64), LDS-staged via global_load_lds
// width-16 (4 issues/K-step), 8 ds_read_b128 + 16 MFMA per K-step, 2 barriers.
template<bool OUT_BF16>
__global__ __launch_bounds__(256) void gemm_lds(
    const unsigned short* __restrict__ A, const unsigned short* __restrict__ B,
    const float* __restrict__ bias, void* __restrict__ Cout,
    int M, int N, int K)
{
  __shared__ unsigned short lsA[128 * 32];  // 8 KB
  __shared__ unsigned short lsB[128 * 32];  // 8 KB
  const int tid  = threadIdx.x;
  const int lane = tid & 63, wid = tid >> 6;
  const int g = lane >> 4, lr = lane & 15;
  const int m0 = blockIdx.x * 128, n0 = blockIdx.y * 128;
  const int wm = (wid >> 1) * 64,  wn = (wid & 1) * 64;
  f32x4 acc[4][4] = {};

  // staging: thread t -> row t/4 (+64 on 2nd issue), col (t%4)*8; LDS linear in t
  const int srow = tid >> 2, scol = (tid & 3) * 8;
  const unsigned short* gA = A + (size_t)(m0 + srow) * K + scol;
  const unsigned short* gB = B + (size_t)(n0 + srow) * K + scol;
  unsigned short* dA = lsA + wid * 512;   // wave-uniform LDS base (ushorts)
  unsigned short* dB = lsB + wid * 512;

  for (int k0 = 0; k0 < K; k0 += 32) {
    gload16(gA + k0,                 dA);
    gload16(gA + k0 + (size_t)64 * K, dA + 2048);
    gload16(gB + k0,                 dB);
    gload16(gB + k0 + (size_t)64 * K, dB + 2048);
    __syncthreads();   // drains vmcnt: staged tile visible to all waves
    s16x8 a[4], b[4];
#pragma unroll
    for (int i = 0; i < 4; ++i)
      a[i] = *reinterpret_cast<const s16x8*>(&lsA[(wm + i * 16 + lr) * 32 + g * 8]);
#pragma unroll
    for (int j = 0; j < 4; ++j)
      b[j] = *reinterpret_cast<const s16x8*>(&lsB[(wn + j * 16 + lr) * 32 + g * 8]);
#pragma unroll
    for (int i = 0; i < 4; ++i)
#pragma unroll
      for (int j = 0; j < 4; ++j)
        acc[i][j] = mfma32(a[i], b[j], acc[i][j]);
    __syncthreads();   // all reads done before next-iter staging overwrites
  }
#pragma unroll
  for (int i = 0; i < 4; ++i)
#pragma unroll
    for (int j = 0; j < 4; ++j) {
      const int col  = n0 + wn + j * 16 + lr;
      const float bv = bias[col];
      const int row0 = m0 + wm + i * 16 + g * 4;
#pragma unroll
      for (int r = 0; r < 4; ++r) {
        float v = acc[i][j][r] + bv;
        if (OUT_BF16)
          reinterpret_cast<unsigned short*>(Cout)[(size_t)(row0 + r) * N + col] = f2bf(v);
        else
          reinterpret_cast<float*>(Cout)[(size_t)(row0 + r) * N + col] = v;
      }
    }
}

// Flash MQA, swapped QK^T, QBLK=32 (two 16-q subtiles per wave).
// Q/K/V come from the fused projection buffer qkv [B*S, 2304]:
//   q = row[h*128 .. +128), k = row[2048..2176), v = row[2176..2304).
// Per kv-step the 4 K vector loads + 32 V scalar loads are SHARED by both subtiles.
// S^T[kv][q] frag: kv=g*4+r, q=lr -> softmax reduce = 4 regs + shfl_xor(16,32).
// Defer-max (T13, THR=8). Output transposed: OT[b][h*128+d][q].
__global__ __launch_bounds__(64) void mqa_attn(
    const unsigned short* __restrict__ qkv,  // [B*S, 2304] bf16
    unsigned short* __restrict__ OT)         // [B, 2048, S] bf16
{
  const int qt = gridDim.x - 1 - blockIdx.x;  // longest blocks first
  const int h  = blockIdx.y;
  const int b  = blockIdx.z;
  const int lane = threadIdx.x;
  const int g = lane >> 4, lr = lane & 15;
  const int q0 = qt * 32;

  const unsigned short* Kb = qkv + (size_t)b * SEQ * PW + 2048;
  const unsigned short* Vb = qkv + (size_t)b * SEQ * PW + 2176;

  s16x8 qf[2][4];
  int qglob[2], dt[2];
#pragma unroll
  for (int s = 0; s < 2; ++s) {
    qglob[s] = q0 + s * 16 + lr;
    dt[s]    = qt * 2 + s;
    const unsigned short* Qb =
        qkv + (size_t)(b * SEQ + q0 + s * 16 + lr) * PW + h * HDIM;
#pragma unroll
    for (int c = 0; c < 4; ++c)
      qf[s][c] = *reinterpret_cast<const s16x8*>(Qb + c * 32 + g * 8);
  }

  float m[2] = {-1e30f, -1e30f}, lsum[2] = {0.f, 0.f};
  f32x4 acc[2][8] = {};
  const float scale = 0.08838834764831845f;  // 1/sqrt(128)

  const int jmax = qt * 2 + 1;
  for (int j = 0; j <= jmax; ++j) {
    const int k0 = j * 16;
    s16x8 kf[4];
#pragma unroll
    for (int c = 0; c < 4; ++c)
      kf[c] = *reinterpret_cast<const s16x8*>(
          Kb + (size_t)(k0 + lr) * PW + c * 32 + g * 8);
    s16x4 pb[2];
#pragma unroll
    for (int s = 0; s < 2; ++s) {
      f32x4 sc = {0.f, 0.f, 0.f, 0.f};
#pragma unroll
      for (int c = 0; c < 4; ++c) sc = mfma32(kf[c], qf[s][c], sc);
      float sv[4];
      if (j >= dt[s]) {            // diagonal or beyond: apply causal mask
#pragma unroll
        for (int r = 0; r < 4; ++r) {
          const int kv = k0 + g * 4 + r;
          sv[r] = (kv <= qglob[s]) ? sc[r] * scale : -1e30f;
        }
      } else {                     // full tile, no mask
#pragma unroll
        for (int r = 0; r < 4; ++r) sv[r] = sc[r] * scale;
      }
      float tmax = fmaxf(fmaxf(sv[0], sv[1]), fmaxf(sv[2], sv[3]));
      tmax = fmaxf(tmax, __shfl_xor(tmax, 16));
      tmax = fmaxf(tmax, __shfl_xor(tmax, 32));
      if (__any(tmax > m[s] + 8.f)) {   // defer-max rescale
        const float mnew  = fmaxf(m[s], tmax);
        const float alpha = __expf(m[s] - mnew);
        lsum[s] *= alpha;
#pragma unroll
        for (int t = 0; t < 8; ++t)
#pragma unroll
          for (int r = 0; r < 4; ++r) acc[s][t][r] *= alpha;
        m[s] = mnew;
      }
      float p[4], ts = 0.f;
#pragma unroll
      for (int r = 0; r < 4; ++r) { p[r] = __expf(sv[r] - m[s]); ts += p[r]; }
      ts += __shfl_xor(ts, 16);
      ts += __shfl_xor(ts, 32);
      lsum[s] += ts;
#pragma unroll
      for (int r = 0; r < 4; ++r) pb[s][r] = (short)f2bf(p[r]);
    }
    // PV: awT[d][q] += V^T(16d x 16kv) * P^T(16kv x 16q); V frags shared by both subtiles
#pragma unroll
    for (int t = 0; t < 8; ++t) {
      s16x4 vf;
#pragma unroll
      for (int e = 0; e < 4; ++e)
        vf[e] = (short)Vb[(size_t)(k0 + g * 4 + e) * PW + t * 16 + lr];
      acc[0][t] = mfma16(vf, pb[0], acc[0][t]);
      acc[1][t] = mfma16(vf, pb[1], acc[1][t]);
    }
  }
#pragma unroll
  for (int s = 0; s < 2; ++s) {
    const float inv = 1.0f / lsum[s];
#pragma unroll
    for (int t = 0; t < 8; ++t)
#pragma unroll
      for (int r = 0; r < 4; ++r) {
        const int d = h * HDIM + t * 16 + g * 4 + r;
        OT[(size_t)(b * HIDDEN + d) * SEQ + qglob[s]] = f2bf(acc[s][t][r] * inv);
      }
  }
}

extern "C" void kernel_launch(void* const* d_in, const int* in_sizes, int n_in,
                              void* d_out, int out_size, void* d_ws, size_t ws_size,
                              hipStream_t stream) {
  (void)in_sizes; (void)n_in; (void)out_size;
  const float* x    = (const float*)d_in[0];
  // d_in[1] = attention_mask (causal tril) — hardcoded in mqa_attn
  const float* qw_w = (const float*)d_in[2];
  const float* qw_b = (const float*)d_in[3];
  const float* kw_w = (const float*)d_in[4];
  const float* kw_b = (const float*)d_in[5];
  const float* vw_w = (const float*)d_in[6];
  const float* vw_b = (const float*)d_in[7];
  const float* ow_w = (const float*)d_in[8];
  const float* ow_b = (const float*)d_in[9];
  float* out = (float*)d_out;

  // ws layout (peak 26,223,616 B < proven-working 27.26 MB):
  //   phase 1 (proj):  xb   ws[0, 16.78M)        wqkv ws[16.78M, 26.21M)
  //                    bqkv ws[26.21M, +9216)
  //   phase 2 (post):  owb  ws[0, 8.39M)   (cast after proj; xb dead)
  //                    awT  ws[8.39M, 25.17M) (attn out; over dead xb/wqkv)
  // d_out scratch: qkvx [4096, 2304] bf16 = 18.87 MB at ob[0] (dead before O-proj
  // overwrites d_out). All scratch written-before-read every call (graph-safe).
  if (ws_size < 26223616) return;  // clean fail signal rather than a fault
  char* ob = (char*)d_out;
  char* ws = (char*)d_ws;
  unsigned short* xb   = (unsigned short*)(ws);
  unsigned short* wqkv = (unsigned short*)(ws + 16777216);
  float*          bqkv = (float*)        (ws + 26214400);
  unsigned short* owb  = (unsigned short*)(ws);
  unsigned short* awT  = (unsigned short*)(ws + 8388608);
  unsigned short* qkvx = (unsigned short*)(ob);

  cast_f32_to_bf16<<<8192, 256, 0, stream>>>(x,    xb,   2097152);
  cast_f32_to_bf16<<<4096, 256, 0, stream>>>(qw_w, wqkv,            1048576);
  cast_f32_to_bf16<<< 256, 256, 0, stream>>>(kw_w, wqkv + 4194304,    65536);
  cast_f32_to_bf16<<< 256, 256, 0, stream>>>(vw_w, wqkv + 4456448,    65536);
  concat_bias<<<9, 256, 0, stream>>>(qw_b, kw_b, vw_b, bqkv);

  // fused QKV projection: [4096,2048] x [2304,2048]^T -> [4096,2304]
  gemm_lds<true ><<<dim3(32, 18), 256, 0, stream>>>(xb, wqkv, bqkv, qkvx, MTOT, PW, HIDDEN);

  // ow cast after proj (xb dead), before O-proj
  cast_f32_to_bf16<<<4096, 256, 0, stream>>>(ow_w, owb, 1048576);

  mqa_attn<<<dim3(SEQ / 32, NHEADS, BATCH), 64, 0, stream>>>(qkvx, awT);

  // O-proj: [4096,2048] x [2048,2048]^T -> fp32 out (overwrites all of d_out)
  gemm_lds<false><<<dim3(32, 16), 256, 0, stream>>>(awT, owb, ow_b, out, MTOT, HIDDEN, HIDDEN);
}

// Round 8
// 319.141 us; speedup vs baseline: 3.2776x; 1.0015x over previous
//
#include <hip/hip_runtime.h>
#include <stdint.h>

#define HIDDEN 2048
#define NHEADS 16
#define HDIM 128
#define BATCH 2
#define SEQ 2048
#define MTOT (BATCH*SEQ)   // 4096
#define PW 2304            // fused qkv projection width (2048 q + 128 k + 128 v)

typedef __attribute__((ext_vector_type(4))) float f32x4;
typedef __attribute__((ext_vector_type(8))) short s16x8;
typedef __attribute__((ext_vector_type(4))) short s16x4;

// round-to-nearest-even f32 -> bf16 bits
static __device__ __forceinline__ unsigned short f2bf(float f) {
  unsigned u = __float_as_uint(f);
  u += 0x7fff + ((u >> 16) & 1);
  return (unsigned short)(u >> 16);
}

static __device__ __forceinline__ f32x4 mfma32(s16x8 a, s16x8 b, f32x4 c) {
  return __builtin_amdgcn_mfma_f32_16x16x32_bf16(a, b, c, 0, 0, 0);
}
static __device__ __forceinline__ f32x4 mfma16(s16x4 a, s16x4 b, f32x4 c) {
  return __builtin_amdgcn_mfma_f32_16x16x16bf16_1k(a, b, c, 0, 0, 0);
}

// async global->LDS, 16B per lane; lds ptr must be wave-uniform (dest = base + lane*16B)
static __device__ __forceinline__ void gload16(const unsigned short* g, unsigned short* l) {
  __builtin_amdgcn_global_load_lds(
      (const __attribute__((address_space(1))) void*)g,
      (__attribute__((address_space(3))) void*)l, 16, 0, 0);
}

__global__ void cast_f32_to_bf16(const float* __restrict__ in,
                                 unsigned short* __restrict__ out, int n4) {
  int i = blockIdx.x * blockDim.x + threadIdx.x;
  if (i >= n4) return;
  float4 v = reinterpret_cast<const float4*>(in)[i];
  ushort4 o;
  o.x = f2bf(v.x); o.y = f2bf(v.y); o.z = f2bf(v.z); o.w = f2bf(v.w);
  reinterpret_cast<ushort4*>(out)[i] = o;
}

__global__ void concat_bias(const float* __restrict__ qb, const float* __restrict__ kb,
                            const float* __restrict__ vb, float* __restrict__ o) {
  int i = blockIdx.x * 256 + threadIdx.x;
  if (i < 2048) o[i] = qb[i];
  else if (i < 2176) o[i] = kb[i - 2048];
  else if (i < 2304) o[i] = vb[i - 2176];
}

// m97-structure GEMM: C[m,n] = sum_k A[m,k]*B[n,k] + bias[n], A/B bf16 row-major.
// 128x128 block tile, BK=32, 4 waves (2x2 of 64x64), LDS-staged via global_load_lds
// width-16 (4 issues/K-step), 8 ds_read_b128 + 16 MFMA per K-step, 2 barriers.
template<bool OUT_BF16>
__global__ __launch_bounds__(256) void gemm_lds(
    const unsigned short* __restrict__ A, const unsigned short* __restrict__ B,
    const float* __restrict__ bias, void* __restrict__ Cout,
    int M, int N, int K)
{
  __shared__ unsigned short lsA[128 * 32];  // 8 KB
  __shared__ unsigned short lsB[128 * 32];  // 8 KB
  const int tid  = threadIdx.x;
  const int lane = tid & 63, wid = tid >> 6;
  const int g = lane >> 4, lr = lane & 15;
  const int m0 = blockIdx.x * 128, n0 = blockIdx.y * 128;
  const int wm = (wid >> 1) * 64,  wn = (wid & 1) * 64;
  f32x4 acc[4][4] = {};

  // staging: thread t -> row t/4 (+64 on 2nd issue), col (t%4)*8; LDS linear in t
  const int srow = tid >> 2, scol = (tid & 3) * 8;
  const unsigned short* gA = A + (size_t)(m0 + srow) * K + scol;
  const unsigned short* gB = B + (size_t)(n0 + srow) * K + scol;
  unsigned short* dA = lsA + wid * 512;   // wave-uniform LDS base (ushorts)
  unsigned short* dB = lsB + wid * 512;

  for (int k0 = 0; k0 < K; k0 += 32) {
    gload16(gA + k0,                 dA);
    gload16(gA + k0 + (size_t)64 * K, dA + 2048);
    gload16(gB + k0,                 dB);
    gload16(gB + k0 + (size_t)64 * K, dB + 2048);
    __syncthreads();   // drains vmcnt: staged tile visible to all waves
    s16x8 a[4], b[4];
#pragma unroll
    for (int i = 0; i < 4; ++i)
      a[i] = *reinterpret_cast<const s16x8*>(&lsA[(wm + i * 16 + lr) * 32 + g * 8]);
#pragma unroll
    for (int j = 0; j < 4; ++j)
      b[j] = *reinterpret_cast<const s16x8*>(&lsB[(wn + j * 16 + lr) * 32 + g * 8]);
#pragma unroll
    for (int i = 0; i < 4; ++i)
#pragma unroll
      for (int j = 0; j < 4; ++j)
        acc[i][j] = mfma32(a[i], b[j], acc[i][j]);
    __syncthreads();   // all reads done before next-iter staging overwrites
  }
#pragma unroll
  for (int i = 0; i < 4; ++i)
#pragma unroll
    for (int j = 0; j < 4; ++j) {
      const int col  = n0 + wn + j * 16 + lr;
      const float bv = bias[col];
      const int row0 = m0 + wm + i * 16 + g * 4;
#pragma unroll
      for (int r = 0; r < 4; ++r) {
        float v = acc[i][j][r] + bv;
        if (OUT_BF16)
          reinterpret_cast<unsigned short*>(Cout)[(size_t)(row0 + r) * N + col] = f2bf(v);
        else
          reinterpret_cast<float*>(Cout)[(size_t)(row0 + r) * N + col] = v;
      }
    }
}

// Flash MQA, swapped QK^T, QBLK=32 per wave (two 16-q subtiles), 4 waves/block.
// Each wave independently processes q-tile qt = bt*4 + wid (no barriers/LDS) —
// 4-wave blocks exist purely to lift per-CU occupancy past the 1-wave-block
// block-slot cap (round-5 structure, proven numerics, at 2x residency).
// Per kv-step the 4 K vector loads + 32 V scalar loads are SHARED by both subtiles.
// S^T[kv][q] frag: kv=g*4+r, q=lr -> softmax reduce = 4 regs + shfl_xor(16,32).
// Defer-max (T13, THR=8). Output transposed: OT[b][h*128+d][q].
__global__ __launch_bounds__(256) void mqa_attn(
    const unsigned short* __restrict__ qkv,  // [B*S, 2304] bf16
    unsigned short* __restrict__ OT)         // [B, 2048, S] bf16
{
  const int bt = gridDim.x - 1 - blockIdx.x;  // longest blocks first
  const int h  = blockIdx.y;
  const int b  = blockIdx.z;
  const int lane = threadIdx.x & 63, wid = threadIdx.x >> 6;
  const int qt = bt * 4 + wid;               // this wave's 32-row q tile
  const int g = lane >> 4, lr = lane & 15;
  const int q0 = qt * 32;

  const unsigned short* Kb = qkv + (size_t)b * SEQ * PW + 2048;
  const unsigned short* Vb = qkv + (size_t)b * SEQ * PW + 2176;

  s16x8 qf[2][4];
  int qglob[2], dt[2];
#pragma unroll
  for (int s = 0; s < 2; ++s) {
    qglob[s] = q0 + s * 16 + lr;
    dt[s]    = qt * 2 + s;
    const unsigned short* Qb =
        qkv + (size_t)(b * SEQ + q0 + s * 16 + lr) * PW + h * HDIM;
#pragma unroll
    for (int c = 0; c < 4; ++c)
      qf[s][c] = *reinterpret_cast<const s16x8*>(Qb + c * 32 + g * 8);
  }

  float m[2] = {-1e30f, -1e30f}, lsum[2] = {0.f, 0.f};
  f32x4 acc[2][8] = {};
  const float scale = 0.08838834764831845f;  // 1/sqrt(128)

  const int jmax = qt * 2 + 1;
  for (int j = 0; j <= jmax; ++j) {
    const int k0 = j * 16;
    s16x8 kf[4];
#pragma unroll
    for (int c = 0; c < 4; ++c)
      kf[c] = *reinterpret_cast<const s16x8*>(
          Kb + (size_t)(k0 + lr) * PW + c * 32 + g * 8);
    s16x4 pb[2];
#pragma unroll
    for (int s = 0; s < 2; ++s) {
      f32x4 sc = {0.f, 0.f, 0.f, 0.f};
#pragma unroll
      for (int c = 0; c < 4; ++c) sc = mfma32(kf[c], qf[s][c], sc);
      float sv[4];
      if (j >= dt[s]) {            // diagonal or beyond: apply causal mask
#pragma unroll
        for (int r = 0; r < 4; ++r) {
          const int kv = k0 + g * 4 + r;
          sv[r] = (kv <= qglob[s]) ? sc[r] * scale : -1e30f;
        }
      } else {                     // full tile, no mask
#pragma unroll
        for (int r = 0; r < 4; ++r) sv[r] = sc[r] * scale;
      }
      float tmax = fmaxf(fmaxf(sv[0], sv[1]), fmaxf(sv[2], sv[3]));
      tmax = fmaxf(tmax, __shfl_xor(tmax, 16));
      tmax = fmaxf(tmax, __shfl_xor(tmax, 32));
      if (__any(tmax > m[s] + 8.f)) {   // defer-max rescale
        const float mnew  = fmaxf(m[s], tmax);
        const float alpha = __expf(m[s] - mnew);
        lsum[s] *= alpha;
#pragma unroll
        for (int t = 0; t < 8; ++t)
#pragma unroll
          for (int r = 0; r < 4; ++r) acc[s][t][r] *= alpha;
        m[s] = mnew;
      }
      float p[4], ts = 0.f;
#pragma unroll
      for (int r = 0; r < 4; ++r) { p[r] = __expf(sv[r] - m[s]); ts += p[r]; }
      ts += __shfl_xor(ts, 16);
      ts += __shfl_xor(ts, 32);
      lsum[s] += ts;
#pragma unroll
      for (int r = 0; r < 4; ++r) pb[s][r] = (short)f2bf(p[r]);
    }
    // PV: awT[d][q] += V^T(16d x 16kv) * P^T(16kv x 16q); V frags shared by both subtiles
#pragma unroll
    for (int t = 0; t < 8; ++t) {
      s16x4 vf;
#pragma unroll
      for (int e = 0; e < 4; ++e)
        vf[e] = (short)Vb[(size_t)(k0 + g * 4 + e) * PW + t * 16 + lr];
      acc[0][t] = mfma16(vf, pb[0], acc[0][t]);
      acc[1][t] = mfma16(vf, pb[1], acc[1][t]);
    }
  }
#pragma unroll
  for (int s = 0; s < 2; ++s) {
    const float inv = 1.0f / lsum[s];
#pragma unroll
    for (int t = 0; t < 8; ++t)
#pragma unroll
      for (int r = 0; r < 4; ++r) {
        const int d = h * HDIM + t * 16 + g * 4 + r;
        OT[(size_t)(b * HIDDEN + d) * SEQ + qglob[s]] = f2bf(acc[s][t][r] * inv);
      }
  }
}

extern "C" void kernel_launch(void* const* d_in, const int* in_sizes, int n_in,
                              void* d_out, int out_size, void* d_ws, size_t ws_size,
                              hipStream_t stream) {
  (void)in_sizes; (void)n_in; (void)out_size;
  const float* x    = (const float*)d_in[0];
  // d_in[1] = attention_mask (causal tril) — hardcoded in mqa_attn
  const float* qw_w = (const float*)d_in[2];
  const float* qw_b = (const float*)d_in[3];
  const float* kw_w = (const float*)d_in[4];
  const float* kw_b = (const float*)d_in[5];
  const float* vw_w = (const float*)d_in[6];
  const float* vw_b = (const float*)d_in[7];
  const float* ow_w = (const float*)d_in[8];
  const float* ow_b = (const float*)d_in[9];
  float* out = (float*)d_out;

  // ws layout (peak 26,223,616 B < proven-working 27.26 MB):
  //   phase 1 (proj):  xb   ws[0, 16.78M)        wqkv ws[16.78M, 26.21M)
  //                    bqkv ws[26.21M, +9216)
  //   phase 2 (post):  owb  ws[0, 8.39M)   (cast after proj; xb dead)
  //                    awT  ws[8.39M, 25.17M) (attn out; over dead xb/wqkv)
  // d_out scratch: qkvx [4096, 2304] bf16 = 18.87 MB at ob[0] (dead before O-proj
  // overwrites d_out). All scratch written-before-read every call (graph-safe).
  if (ws_size < 26223616) return;  // clean fail signal rather than a fault
  char* ob = (char*)d_out;
  char* ws = (char*)d_ws;
  unsigned short* xb   = (unsigned short*)(ws);
  unsigned short* wqkv = (unsigned short*)(ws + 16777216);
  float*          bqkv = (float*)        (ws + 26214400);
  unsigned short* owb  = (unsigned short*)(ws);
  unsigned short* awT  = (unsigned short*)(ws + 8388608);
  unsigned short* qkvx = (unsigned short*)(ob);

  cast_f32_to_bf16<<<8192, 256, 0, stream>>>(x,    xb,   2097152);
  cast_f32_to_bf16<<<4096, 256, 0, stream>>>(qw_w, wqkv,            1048576);
  cast_f32_to_bf16<<< 256, 256, 0, stream>>>(kw_w, wqkv + 4194304,    65536);
  cast_f32_to_bf16<<< 256, 256, 0, stream>>>(vw_w, wqkv + 4456448,    65536);
  concat_bias<<<9, 256, 0, stream>>>(qw_b, kw_b, vw_b, bqkv);

  // fused QKV projection: [4096,2048] x [2304,2048]^T -> [4096,2304]
  gemm_lds<true ><<<dim3(32, 18), 256, 0, stream>>>(xb, wqkv, bqkv, qkvx, MTOT, PW, HIDDEN);

  // ow cast after proj (xb dead), before O-proj
  cast_f32_to_bf16<<<4096, 256, 0, stream>>>(ow_w, owb, 1048576);

  // 4 independent waves per block (q-tiles bt*4+wid) purely for occupancy
  mqa_attn<<<dim3(SEQ / 128, NHEADS, BATCH), 256, 0, stream>>>(qkvx, awT);

  // O-proj: [4096,2048] x [2048,2048]^T -> fp32 out (overwrites all of d_out)
  gemm_lds<false><<<dim3(32, 16), 256, 0, stream>>>(awT, owb, ow_b, out, MTOT, HIDDEN, HIDDEN);
}